// Round 3
// baseline (572.114 us; speedup 1.0000x reference)
//
#include <hip/hip_runtime.h>

typedef unsigned short u16;
typedef unsigned int u32;
typedef __attribute__((ext_vector_type(8))) short bf16x8;
typedef __attribute__((ext_vector_type(4))) float f32x4;

#define MFMA16(a, b, c) __builtin_amdgcn_mfma_f32_16x16x32_bf16((a), (b), (c), 0, 0, 0)

constexpr int D = 1024;       // d_model
constexpr int NH = 16;        // heads
constexpr int HD = 64;        // head dim
constexpr int BB = 4;         // batch
constexpr int SS = 2048;      // seq len
constexpr int BH = BB * NH;   // 64
constexpr int MTOK = BB * SS; // 8192
constexpr float SCALE_LOG2E = 0.125f * 1.44269504088896340736f; // HD^-0.5 * log2(e)

__device__ __forceinline__ u16 f32_bf16(float f) {
  union { float f; u32 u; } v; v.f = f;
  u32 u = v.u;
  u += 0x7FFFu + ((u >> 16) & 1u); // RNE
  return (u16)(u >> 16);
}

__device__ __forceinline__ void gload_lds16(const u16* g, u16* l) {
  __builtin_amdgcn_global_load_lds(
      (const __attribute__((address_space(1))) u32*)g,
      (__attribute__((address_space(3))) u32*)l, 16, 0, 0);
}

// ---------------- fp32 -> bf16 elementwise convert ----------------
__global__ __launch_bounds__(256)
void cvt_bf16(const float* __restrict__ in, u16* __restrict__ out, int n4) {
  int i = blockIdx.x * 256 + threadIdx.x;
  const int stride = gridDim.x * 256;
  for (; i < n4; i += stride) {
    float4 v = reinterpret_cast<const float4*>(in)[i];
    u32 lo = (u32)f32_bf16(v.x) | ((u32)f32_bf16(v.y) << 16);
    u32 hi = (u32)f32_bf16(v.z) | ((u32)f32_bf16(v.w) << 16);
    reinterpret_cast<uint2*>(out)[i] = make_uint2(lo, hi);
  }
}

// ---------------- fp32 [R][C] -> bf16 [C][R] transpose ----------------
__global__ __launch_bounds__(256)
void transpose_bf16(const float* __restrict__ in, u16* __restrict__ out, int R, int C) {
  __shared__ float tile[32][33];
  const int c0 = blockIdx.x * 32, r0 = blockIdx.y * 32;
  const int tx = threadIdx.x, ty = threadIdx.y;
#pragma unroll
  for (int i = 0; i < 4; i++)
    tile[ty + 8 * i][tx] = in[(size_t)(r0 + ty + 8 * i) * C + c0 + tx];
  __syncthreads();
#pragma unroll
  for (int i = 0; i < 4; i++)
    out[(size_t)(c0 + ty + 8 * i) * R + r0 + tx] = f32_bf16(tile[tx][ty + 8 * i]);
}

// ---------------- bf16 GEMM: C[M][N] = A[M][K] * Bt[N][K]^T + bias ----------------
// MODE 0: scatter into Q [BH][S][64], K [BH][S][64], Vt [BH][64][S] (bf16)
// MODE 1: fp32 out [M][N]
template <int MODE>
__global__ __launch_bounds__(256)
void gemm_bf16(const u16* __restrict__ A, const u16* __restrict__ Bt,
               const float* __restrict__ bias,
               u16* __restrict__ q_out, u16* __restrict__ k_out,
               u16* __restrict__ vt_out, float* __restrict__ f_out,
               int M, int N, int K) {
  constexpr int BK = 32;
  __shared__ u16 lds_a[128 * BK];
  __shared__ u16 lds_b[128 * BK];
  const int m0 = blockIdx.x * 128;
  const int n0 = blockIdx.y * 128;
  const int t = threadIdx.x;
  const int lane = t & 63;
  const int w = t >> 6;
  const int wr = w >> 1, wc = w & 1;        // 2x2 wave grid, 64x64 per wave
  const int fr = lane & 15, fq = lane >> 4; // fragment row/col group

  const u16* ga0 = A + (size_t)(m0 + (t >> 2)) * K + (t & 3) * 8;
  const u16* ga1 = ga0 + (size_t)64 * K;
  const u16* gb0 = Bt + (size_t)(n0 + (t >> 2)) * K + (t & 3) * 8;
  const u16* gb1 = gb0 + (size_t)64 * K;
  u16* la0 = lds_a + t * 8;
  u16* la1 = lds_a + (t + 256) * 8;
  u16* lb0 = lds_b + t * 8;
  u16* lb1 = lds_b + (t + 256) * 8;

  f32x4 acc[4][4] = {};

  for (int k0 = 0; k0 < K; k0 += BK) {
    __syncthreads();
    gload_lds16(ga0, la0);
    gload_lds16(ga1, la1);
    gload_lds16(gb0, lb0);
    gload_lds16(gb1, lb1);
    ga0 += BK; ga1 += BK; gb0 += BK; gb1 += BK;
    __syncthreads();
    bf16x8 af[4], bfr[4];
#pragma unroll
    for (int i = 0; i < 4; i++)
      af[i] = *reinterpret_cast<const bf16x8*>(lds_a + (wr * 64 + i * 16 + fr) * BK + fq * 8);
#pragma unroll
    for (int i = 0; i < 4; i++)
      bfr[i] = *reinterpret_cast<const bf16x8*>(lds_b + (wc * 64 + i * 16 + fr) * BK + fq * 8);
#pragma unroll
    for (int i = 0; i < 4; i++)
#pragma unroll
      for (int j = 0; j < 4; j++)
        acc[i][j] = MFMA16(af[i], bfr[j], acc[i][j]);
  }

#pragma unroll
  for (int i = 0; i < 4; i++) {
#pragma unroll
    for (int j = 0; j < 4; j++) {
      const int ncol = n0 + wc * 64 + j * 16 + fr;
      const float bs = bias[ncol];
#pragma unroll
      for (int r = 0; r < 4; r++) {
        const int mrow = m0 + wr * 64 + i * 16 + fq * 4 + r;
        const float vv = acc[i][j][r] + bs;
        if (MODE == 0) {
          const int which = ncol >> 10;
          const int rem = ncol & 1023;
          const int hh = rem >> 6, dd = rem & 63;
          const int bb = mrow >> 11, ss = mrow & 2047;
          const int bh = bb * 16 + hh;
          const u16 bv = f32_bf16(vv);
          if (which == 0)
            q_out[((size_t)bh * SS + ss) * HD + dd] = bv;
          else if (which == 1)
            k_out[((size_t)bh * SS + ss) * HD + dd] = bv;
          else
            vt_out[((size_t)bh * HD + dd) * SS + ss] = bv;
        } else {
          f_out[(size_t)mrow * N + ncol] = vv;
        }
      }
    }
  }
}

// ---------------- causal flash attention ----------------
// Q,K: [BH][S][64] bf16 ; Vt: [BH][64][S] bf16 ; vals: [B][S][D] bf16
__global__ __launch_bounds__(256)
void attn_fwd(const u16* __restrict__ Qb, const u16* __restrict__ Kb,
              const u16* __restrict__ Vt, u16* __restrict__ vals) {
  const int qt = blockIdx.x;  // q tile (64 rows)
  const int bh = blockIdx.y;  // batch*head
  const u16* Qp = Qb + (size_t)bh * SS * HD;
  const u16* Kp = Kb + (size_t)bh * SS * HD;
  const u16* Vp = Vt + (size_t)bh * HD * SS;
  const int t = threadIdx.x, lane = t & 63, w = t >> 6;
  const int fr = lane & 15, fq = lane >> 4;
  const int q0 = qt * 64;
  const int qbase = q0 + w * 16; // this wave's 16 q rows

  __shared__ u16 plds[4][16][72]; // per-wave P tile, padded (+8) vs bank conflicts
  u16* myp = &plds[w][0][0];

  // Q fragments held in registers for the whole kernel
  bf16x8 aq[2];
#pragma unroll
  for (int kk = 0; kk < 2; kk++)
    aq[kk] = *reinterpret_cast<const bf16x8*>(Qp + (size_t)(qbase + fr) * HD + kk * 32 + fq * 8);

  f32x4 o[4] = {};
  float mrun[4], lrun[4];
#pragma unroll
  for (int j = 0; j < 4; j++) { mrun[j] = -3e38f; lrun[j] = 0.f; }

  for (int kvt = 0; kvt <= qt; ++kvt) {
    const int kv0 = kvt * 64;
    // S = Q K^T  (k-dim = head dim 64 -> 2 mfma per 16x16 C frag)
    f32x4 sc[4] = {};
#pragma unroll
    for (int kf = 0; kf < 4; kf++) {
#pragma unroll
      for (int kk = 0; kk < 2; kk++) {
        bf16x8 bk = *reinterpret_cast<const bf16x8*>(
            Kp + (size_t)(kv0 + kf * 16 + fr) * HD + kk * 32 + fq * 8);
        sc[kf] = MFMA16(aq[kk], bk, sc[kf]);
      }
    }
    // causal mask: only the diagonal tile needs it
    if (kvt == qt) {
#pragma unroll
      for (int kf = 0; kf < 4; kf++)
#pragma unroll
        for (int j = 0; j < 4; j++) {
          const int keyl = kf * 16 + fr;
          const int ql = w * 16 + fq * 4 + j;
          if (keyl > ql) sc[kf][j] = -3e38f;
        }
    }
    // online softmax per q-row (row j lives in 16-lane group, reg j)
#pragma unroll
    for (int j = 0; j < 4; j++) {
      float mj = fmaxf(fmaxf(sc[0][j], sc[1][j]), fmaxf(sc[2][j], sc[3][j]));
#pragma unroll
      for (int off = 1; off < 16; off <<= 1)
        mj = fmaxf(mj, __shfl_xor(mj, off, 64));
      const float mnew = fmaxf(mrun[j], mj);
      const float alpha = exp2f((mrun[j] - mnew) * SCALE_LOG2E);
      mrun[j] = mnew;
      float rs = 0.f;
#pragma unroll
      for (int kf = 0; kf < 4; kf++) {
        const float p = exp2f((sc[kf][j] - mnew) * SCALE_LOG2E);
        sc[kf][j] = p;
        rs += p;
      }
#pragma unroll
      for (int off = 1; off < 16; off <<= 1)
        rs += __shfl_xor(rs, off, 64);
      lrun[j] = lrun[j] * alpha + rs;
#pragma unroll
      for (int df = 0; df < 4; df++) o[df][j] *= alpha;
    }
    // P -> per-wave LDS (bf16), then read A-fragments (wave-internal, DS in-order)
#pragma unroll
    for (int kf = 0; kf < 4; kf++)
#pragma unroll
      for (int j = 0; j < 4; j++)
        myp[(fq * 4 + j) * 72 + kf * 16 + fr] = f32_bf16(sc[kf][j]);
    bf16x8 pa[2];
#pragma unroll
    for (int kk = 0; kk < 2; kk++)
      pa[kk] = *reinterpret_cast<const bf16x8*>(myp + fr * 72 + kk * 32 + fq * 8);
    // O += P V   (Vt is [64][S]: key-contiguous B fragments)
#pragma unroll
    for (int df = 0; df < 4; df++) {
#pragma unroll
      for (int kk = 0; kk < 2; kk++) {
        bf16x8 bv = *reinterpret_cast<const bf16x8*>(
            Vp + (size_t)(df * 16 + fr) * SS + kv0 + kk * 32 + fq * 8);
        o[df] = MFMA16(pa[kk], bv, o[df]);
      }
    }
  }

  const int b_ = bh >> 4, h_ = bh & 15;
#pragma unroll
  for (int df = 0; df < 4; df++)
#pragma unroll
    for (int j = 0; j < 4; j++) {
      const float vv = o[df][j] / lrun[j];
      const int qg = qbase + fq * 4 + j;
      vals[((size_t)(b_ * SS + qg)) * D + h_ * HD + df * 16 + fr] = f32_bf16(vv);
    }
}

extern "C" void kernel_launch(void* const* d_in, const int* in_sizes, int n_in,
                              void* d_out, int out_size, void* d_ws, size_t ws_size,
                              hipStream_t stream) {
  const float* x = (const float*)d_in[0];
  const float* Wqkv = (const float*)d_in[1];
  const float* bqkv = (const float*)d_in[2];
  const float* Wout = (const float*)d_in[3];
  const float* bout = (const float*)d_in[4];
  float* out = (float*)d_out;

  char* p = (char*)d_ws;
  u16* xb = (u16*)p;    p += (size_t)MTOK * D * 2;       // 16.8 MB
  u16* wqkvT = (u16*)p; p += (size_t)3 * D * D * 2;      // 6.3 MB
  u16* woutT = (u16*)p; p += (size_t)D * D * 2;          // 2.1 MB
  u16* Qb = (u16*)p;    p += (size_t)BH * SS * HD * 2;   // 16.8 MB
  u16* Kb = (u16*)p;    p += (size_t)BH * SS * HD * 2;   // 16.8 MB
  u16* Vt = (u16*)p;    p += (size_t)BH * SS * HD * 2;   // 16.8 MB
  u16* vals = (u16*)p;  p += (size_t)MTOK * D * 2;       // 16.8 MB  (total ~92 MB)

  cvt_bf16<<<2048, 256, 0, stream>>>(x, xb, MTOK * D / 4);
  transpose_bf16<<<dim3(3 * D / 32, D / 32), dim3(32, 8), 0, stream>>>(Wqkv, wqkvT, D, 3 * D);
  transpose_bf16<<<dim3(D / 32, D / 32), dim3(32, 8), 0, stream>>>(Wout, woutT, D, D);
  gemm_bf16<0><<<dim3(MTOK / 128, 3 * D / 128), 256, 0, stream>>>(
      xb, wqkvT, bqkv, Qb, Kb, Vt, nullptr, MTOK, 3 * D, D);
  attn_fwd<<<dim3(SS / 64, BH), 256, 0, stream>>>(Qb, Kb, Vt, vals);
  gemm_bf16<1><<<dim3(MTOK / 128, D / 128), 256, 0, stream>>>(
      vals, woutT, bout, nullptr, nullptr, nullptr, out, MTOK, D, D);
}

// Round 5
// 274.318 us; speedup vs baseline: 2.0856x; 2.0856x over previous
//
#include <hip/hip_runtime.h>

typedef unsigned short u16;
typedef unsigned int u32;
typedef __attribute__((ext_vector_type(8))) short bf16x8;
typedef __attribute__((ext_vector_type(4))) float f32x4;

#define MFMA16(a, b, c) __builtin_amdgcn_mfma_f32_16x16x32_bf16((a), (b), (c), 0, 0, 0)

constexpr int D = 1024;       // d_model
constexpr int NH = 16;        // heads
constexpr int HD = 64;        // head dim
constexpr int BB = 4;         // batch
constexpr int SS = 2048;      // seq len
constexpr int BH = BB * NH;   // 64
constexpr int MTOK = BB * SS; // 8192
constexpr float SCALE_LOG2E = 0.125f * 1.44269504088896340736f; // HD^-0.5 * log2(e)

__device__ __forceinline__ u16 f32_bf16(float f) {
  union { float f; u32 u; } v; v.f = f;
  u32 u = v.u;
  u += 0x7FFFu + ((u >> 16) & 1u); // RNE
  return (u16)(u >> 16);
}

__device__ __forceinline__ void gload_lds16(const void* g, u16* l) {
  __builtin_amdgcn_global_load_lds(
      (const __attribute__((address_space(1))) u32*)g,
      (__attribute__((address_space(3))) u32*)l, 16, 0, 0);
}

// ---------------- fp32 -> bf16 elementwise convert ----------------
__global__ __launch_bounds__(256)
void cvt_bf16(const float* __restrict__ in, u16* __restrict__ out, int n4) {
  int i = blockIdx.x * 256 + threadIdx.x;
  const int stride = gridDim.x * 256;
  for (; i < n4; i += stride) {
    float4 v = reinterpret_cast<const float4*>(in)[i];
    u32 lo = (u32)f32_bf16(v.x) | ((u32)f32_bf16(v.y) << 16);
    u32 hi = (u32)f32_bf16(v.z) | ((u32)f32_bf16(v.w) << 16);
    reinterpret_cast<uint2*>(out)[i] = make_uint2(lo, hi);
  }
}

// ---------------- fp32 [R][C] -> bf16 [C][R] transpose ----------------
__global__ __launch_bounds__(256)
void transpose_bf16(const float* __restrict__ in, u16* __restrict__ out, int R, int C) {
  __shared__ float tile[32][33];
  const int c0 = blockIdx.x * 32, r0 = blockIdx.y * 32;
  const int tx = threadIdx.x, ty = threadIdx.y;
#pragma unroll
  for (int i = 0; i < 4; i++)
    tile[ty + 8 * i][tx] = in[(size_t)(r0 + ty + 8 * i) * C + c0 + tx];
  __syncthreads();
#pragma unroll
  for (int i = 0; i < 4; i++)
    out[(size_t)(c0 + ty + 8 * i) * R + r0 + tx] = f32_bf16(tile[tx][ty + 8 * i]);
}

// ---------------- bf16 GEMM: C[M][N] = A[M][K] * Bt[N][K]^T + bias ----------------
// MODE 0: scatter into Q (pre-scaled by SCALE*log2e) [BH][S][64], K [BH][S][64],
//         Vt [BH][64][S] (bf16)
// MODE 1: fp32 out [M][N]
template <int MODE>
__global__ __launch_bounds__(256)
void gemm_bf16(const u16* __restrict__ A, const u16* __restrict__ Bt,
               const float* __restrict__ bias,
               u16* __restrict__ q_out, u16* __restrict__ k_out,
               u16* __restrict__ vt_out, float* __restrict__ f_out,
               int M, int N, int K) {
  constexpr int BK = 32;
  __shared__ u16 lds_a[128 * BK];
  __shared__ u16 lds_b[128 * BK];
  const int m0 = blockIdx.x * 128;
  const int n0 = blockIdx.y * 128;
  const int t = threadIdx.x;
  const int lane = t & 63;
  const int w = t >> 6;
  const int wr = w >> 1, wc = w & 1;        // 2x2 wave grid, 64x64 per wave
  const int fr = lane & 15, fq = lane >> 4; // fragment row/col group

  const u16* ga0 = A + (size_t)(m0 + (t >> 2)) * K + (t & 3) * 8;
  const u16* ga1 = ga0 + (size_t)64 * K;
  const u16* gb0 = Bt + (size_t)(n0 + (t >> 2)) * K + (t & 3) * 8;
  const u16* gb1 = gb0 + (size_t)64 * K;
  u16* la0 = lds_a + t * 8;
  u16* la1 = lds_a + (t + 256) * 8;
  u16* lb0 = lds_b + t * 8;
  u16* lb1 = lds_b + (t + 256) * 8;

  f32x4 acc[4][4] = {};

  for (int k0 = 0; k0 < K; k0 += BK) {
    __syncthreads();
    gload_lds16(ga0, la0);
    gload_lds16(ga1, la1);
    gload_lds16(gb0, lb0);
    gload_lds16(gb1, lb1);
    ga0 += BK; ga1 += BK; gb0 += BK; gb1 += BK;
    __syncthreads();
    bf16x8 af[4], bfr[4];
#pragma unroll
    for (int i = 0; i < 4; i++)
      af[i] = *reinterpret_cast<const bf16x8*>(lds_a + (wr * 64 + i * 16 + fr) * BK + fq * 8);
#pragma unroll
    for (int i = 0; i < 4; i++)
      bfr[i] = *reinterpret_cast<const bf16x8*>(lds_b + (wc * 64 + i * 16 + fr) * BK + fq * 8);
#pragma unroll
    for (int i = 0; i < 4; i++)
#pragma unroll
      for (int j = 0; j < 4; j++)
        acc[i][j] = MFMA16(af[i], bfr[j], acc[i][j]);
  }

#pragma unroll
  for (int i = 0; i < 4; i++) {
#pragma unroll
    for (int j = 0; j < 4; j++) {
      const int ncol = n0 + wc * 64 + j * 16 + fr;
      const float bs = bias[ncol];
#pragma unroll
      for (int r = 0; r < 4; r++) {
        const int mrow = m0 + wr * 64 + i * 16 + fq * 4 + r;
        const float vv = acc[i][j][r] + bs;
        if (MODE == 0) {
          const int which = ncol >> 10;
          const int rem = ncol & 1023;
          const int hh = rem >> 6, dd = rem & 63;
          const int bb = mrow >> 11, ss = mrow & 2047;
          const int bh = bb * 16 + hh;
          if (which == 0)
            q_out[((size_t)bh * SS + ss) * HD + dd] = f32_bf16(vv * SCALE_LOG2E);
          else if (which == 1)
            k_out[((size_t)bh * SS + ss) * HD + dd] = f32_bf16(vv);
          else
            vt_out[((size_t)bh * HD + dd) * SS + ss] = f32_bf16(vv);
        } else {
          f_out[(size_t)mrow * N + ncol] = vv;
        }
      }
    }
  }
}

// ---------------- causal flash attention ----------------
// Q (pre-scaled), K: [BH][S][64] bf16 ; Vt: [BH][64][S] bf16 ; vals: [B][S][D] bf16
// Block = q-tile PAIR (pi, 31-pi): exactly 33 kv-tiles per block (uniform work).
// K/V tiles double-buffered in LDS (XOR-swizzled), staged with global_load_lds:
// linear LDS dest + inverse-swizzled GLOBAL source, swizzle applied on ds_read.
__global__ __launch_bounds__(256)
void attn_fwd(const u16* __restrict__ Qb, const u16* __restrict__ Kb,
              const u16* __restrict__ Vt, u16* __restrict__ vals) {
  const int pi = blockIdx.x;  // pair index 0..15 -> q-tiles (pi, 31-pi)
  const int bh = blockIdx.y;  // batch*head
  const u16* Qp = Qb + (size_t)bh * SS * HD;
  const char* Kp = (const char*)(Kb + (size_t)bh * SS * HD);
  const char* Vp = (const char*)(Vt + (size_t)bh * HD * SS);
  const int t = threadIdx.x, lane = t & 63, w = t >> 6;
  const int fr = lane & 15, fq = lane >> 4;
  const int swz = (fr & 7) << 4; // row&7 == fr&7 for all fragment rows used below

  __shared__ u16 kbuf[2][4096]; // [64 rows][128B] swizzled, 8KB each
  __shared__ u16 vbuf[2][4096]; // [64 d-rows][128B keys] swizzled
  __shared__ u16 plds[4][16][72];
  u16* myp = &plds[w][0][0];

  const int qtA = pi, qtB = 31 - pi;
  const int nA = qtA + 1, nTot = nA + qtB + 1; // == 33

  const int lin0 = t * 16; // staging byte offset, round 0

  bf16x8 aq[2];
  {
    const int qbase = qtA * 64 + w * 16;
#pragma unroll
    for (int kk = 0; kk < 2; kk++)
      aq[kk] = *reinterpret_cast<const bf16x8*>(Qp + (size_t)(qbase + fr) * HD + kk * 32 + fq * 8);
  }

  f32x4 o[4] = {};
  float mrun[4], lrun[4];
#pragma unroll
  for (int j = 0; j < 4; j++) { mrun[j] = -3e38f; lrun[j] = 0.f; }

#define STAGE(bufi, kvt_)                                                     \
  {                                                                           \
    _Pragma("unroll")                                                         \
    for (int r = 0; r < 2; r++) {                                             \
      const int lin = lin0 + r * 4096;                                        \
      const int row = lin >> 7, colb = lin & 127;                             \
      const int scol = colb ^ ((row & 7) << 4);                               \
      gload_lds16(Kp + (size_t)((kvt_) * 64 + row) * 128 + scol,              \
                  &kbuf[bufi][lin >> 1]);                                     \
      gload_lds16(Vp + (size_t)row * 4096 + (kvt_) * 128 + scol,              \
                  &vbuf[bufi][lin >> 1]);                                     \
    }                                                                         \
  }

  auto write_out = [&](int qt) {
    const int b_ = bh >> 4, h_ = bh & 15;
    const int qb = qt * 64 + w * 16;
#pragma unroll
    for (int df = 0; df < 4; df++)
#pragma unroll
      for (int j = 0; j < 4; j++) {
        const float vv = o[df][j] / lrun[j];
        const int qg = qb + fq * 4 + j;
        vals[((size_t)(b_ * SS + qg)) * D + h_ * HD + df * 16 + fr] = f32_bf16(vv);
      }
  };

  int cur = 0;
  STAGE(0, 0);
  asm volatile("s_waitcnt vmcnt(0)" ::: "memory");
  __syncthreads();

  for (int ti = 0; ti < nTot; ++ti) {
    const bool segB = ti >= nA;
    const int kvt = segB ? ti - nA : ti;
    const int qt = segB ? qtB : qtA;
    // prefetch next kv tile (kv tiles are qt-independent, so the pipeline
    // runs flat across the segment boundary)
    if (ti + 1 < nTot) {
      const int nk = (ti + 1 >= nA) ? (ti + 1 - nA) : (ti + 1);
      STAGE(cur ^ 1, nk);
    }
    if (ti == nA) { // segment switch: flush A, reset state for B
      write_out(qtA);
      const int qbase = qtB * 64 + w * 16;
#pragma unroll
      for (int kk = 0; kk < 2; kk++)
        aq[kk] = *reinterpret_cast<const bf16x8*>(Qp + (size_t)(qbase + fr) * HD + kk * 32 + fq * 8);
#pragma unroll
      for (int j = 0; j < 4; j++) { mrun[j] = -3e38f; lrun[j] = 0.f; }
#pragma unroll
      for (int df = 0; df < 4; df++) o[df] = f32x4{0.f, 0.f, 0.f, 0.f};
    }

    const char* kb = (const char*)kbuf[cur];
    const char* vb = (const char*)vbuf[cur];

    // S = Q K^T (Q pre-scaled by SCALE*log2e -> scores already in log2 units)
    f32x4 sc[4] = {};
#pragma unroll
    for (int kf = 0; kf < 4; kf++) {
#pragma unroll
      for (int kk = 0; kk < 2; kk++) {
        const int off = (kf * 16 + fr) * 128 + ((kk * 64 + fq * 16) ^ swz);
        bf16x8 bk = *reinterpret_cast<const bf16x8*>(kb + off);
        sc[kf] = MFMA16(aq[kk], bk, sc[kf]);
      }
    }
    // causal mask: diagonal tile only
    if (kvt == qt) {
#pragma unroll
      for (int kf = 0; kf < 4; kf++)
#pragma unroll
        for (int j = 0; j < 4; j++) {
          const int keyl = kf * 16 + fr;
          const int ql = w * 16 + fq * 4 + j;
          if (keyl > ql) sc[kf][j] = -3e38f;
        }
    }
    // online softmax per q-row (row j lives in 16-lane group, reg j)
#pragma unroll
    for (int j = 0; j < 4; j++) {
      float mj = fmaxf(fmaxf(sc[0][j], sc[1][j]), fmaxf(sc[2][j], sc[3][j]));
#pragma unroll
      for (int off = 1; off < 16; off <<= 1)
        mj = fmaxf(mj, __shfl_xor(mj, off, 64));
      const float mnew = fmaxf(mrun[j], mj);
      const float alpha = exp2f(mrun[j] - mnew);
      mrun[j] = mnew;
      float rs = 0.f;
#pragma unroll
      for (int kf = 0; kf < 4; kf++) {
        const float p = exp2f(sc[kf][j] - mnew);
        sc[kf][j] = p;
        rs += p;
      }
#pragma unroll
      for (int off = 1; off < 16; off <<= 1)
        rs += __shfl_xor(rs, off, 64);
      lrun[j] = lrun[j] * alpha + rs;
#pragma unroll
      for (int df = 0; df < 4; df++) o[df][j] *= alpha;
    }
    // P -> per-wave LDS (bf16), then read A-fragments (wave-internal DS ordering)
#pragma unroll
    for (int kf = 0; kf < 4; kf++)
#pragma unroll
      for (int j = 0; j < 4; j++)
        myp[(fq * 4 + j) * 72 + kf * 16 + fr] = f32_bf16(sc[kf][j]);
    bf16x8 pa[2];
#pragma unroll
    for (int kk = 0; kk < 2; kk++)
      pa[kk] = *reinterpret_cast<const bf16x8*>(myp + fr * 72 + kk * 32 + fq * 8);
    // O += P V  (V tile in LDS: [d-row][key] swizzled)
#pragma unroll
    for (int df = 0; df < 4; df++) {
#pragma unroll
      for (int kk = 0; kk < 2; kk++) {
        const int off = (df * 16 + fr) * 128 + ((kk * 64 + fq * 16) ^ swz);
        bf16x8 bv = *reinterpret_cast<const bf16x8*>(vb + off);
        o[df] = MFMA16(pa[kk], bv, o[df]);
      }
    }

    asm volatile("s_waitcnt vmcnt(0)" ::: "memory");
    __syncthreads();
    cur ^= 1;
  }
  write_out(qtB);
#undef STAGE
}

extern "C" void kernel_launch(void* const* d_in, const int* in_sizes, int n_in,
                              void* d_out, int out_size, void* d_ws, size_t ws_size,
                              hipStream_t stream) {
  const float* x = (const float*)d_in[0];
  const float* Wqkv = (const float*)d_in[1];
  const float* bqkv = (const float*)d_in[2];
  const float* Wout = (const float*)d_in[3];
  const float* bout = (const float*)d_in[4];
  float* out = (float*)d_out;

  char* p = (char*)d_ws;
  u16* xb = (u16*)p;    p += (size_t)MTOK * D * 2;       // 16.8 MB
  u16* wqkvT = (u16*)p; p += (size_t)3 * D * D * 2;      // 6.3 MB
  u16* woutT = (u16*)p; p += (size_t)D * D * 2;          // 2.1 MB
  u16* Qb = (u16*)p;    p += (size_t)BH * SS * HD * 2;   // 16.8 MB
  u16* Kb = (u16*)p;    p += (size_t)BH * SS * HD * 2;   // 16.8 MB
  u16* Vt = (u16*)p;    p += (size_t)BH * SS * HD * 2;   // 16.8 MB
  u16* vals = (u16*)p;  p += (size_t)MTOK * D * 2;       // 16.8 MB  (total ~92 MB)

  cvt_bf16<<<2048, 256, 0, stream>>>(x, xb, MTOK * D / 4);
  transpose_bf16<<<dim3(3 * D / 32, D / 32), dim3(32, 8), 0, stream>>>(Wqkv, wqkvT, D, 3 * D);
  transpose_bf16<<<dim3(D / 32, D / 32), dim3(32, 8), 0, stream>>>(Wout, woutT, D, D);
  gemm_bf16<0><<<dim3(MTOK / 128, 3 * D / 128), 256, 0, stream>>>(
      xb, wqkvT, bqkv, Qb, Kb, Vt, nullptr, MTOK, 3 * D, D);
  attn_fwd<<<dim3(16, BH), 256, 0, stream>>>(Qb, Kb, Vt, vals);
  gemm_bf16<1><<<dim3(MTOK / 128, D / 128), 256, 0, stream>>>(
      vals, woutT, bout, nullptr, nullptr, nullptr, out, MTOK, D, D);
}

// Round 6
// 245.170 us; speedup vs baseline: 2.3335x; 1.1189x over previous
//
#include <hip/hip_runtime.h>

typedef unsigned short u16;
typedef unsigned int u32;
typedef __attribute__((ext_vector_type(8))) short bf16x8;
typedef __attribute__((ext_vector_type(4))) float f32x4;

#define MFMA16(a, b, c) __builtin_amdgcn_mfma_f32_16x16x32_bf16((a), (b), (c), 0, 0, 0)

constexpr int D = 1024;       // d_model
constexpr int NH = 16;        // heads
constexpr int HD = 64;        // head dim
constexpr int BB = 4;         // batch
constexpr int SS = 2048;      // seq len
constexpr int BH = BB * NH;   // 64
constexpr int MTOK = BB * SS; // 8192
constexpr float SCALE_LOG2E = 0.125f * 1.44269504088896340736f; // HD^-0.5 * log2(e)

__device__ __forceinline__ u16 f32_bf16(float f) {
  union { float f; u32 u; } v; v.f = f;
  u32 u = v.u;
  u += 0x7FFFu + ((u >> 16) & 1u); // RNE
  return (u16)(u >> 16);
}

// single-instruction transcendental / convert paths (avoid ocml calls)
__device__ __forceinline__ float exp2_fast(float x) {
  float r; asm("v_exp_f32 %0, %1" : "=v"(r) : "v"(x)); return r;
}
__device__ __forceinline__ u16 cvt_bf16_1(float f) {
  u32 r; asm("v_cvt_pk_bf16_f32 %0, %1, %1" : "=v"(r) : "v"(f)); return (u16)r;
}

__device__ __forceinline__ void gload_lds16(const void* g, u16* l) {
  __builtin_amdgcn_global_load_lds(
      (const __attribute__((address_space(1))) u32*)g,
      (__attribute__((address_space(3))) u32*)l, 16, 0, 0);
}

// ---------------- fp32 -> bf16 elementwise convert ----------------
__global__ __launch_bounds__(256)
void cvt_bf16(const float* __restrict__ in, u16* __restrict__ out, int n4) {
  int i = blockIdx.x * 256 + threadIdx.x;
  const int stride = gridDim.x * 256;
  for (; i < n4; i += stride) {
    float4 v = reinterpret_cast<const float4*>(in)[i];
    u32 lo = (u32)f32_bf16(v.x) | ((u32)f32_bf16(v.y) << 16);
    u32 hi = (u32)f32_bf16(v.z) | ((u32)f32_bf16(v.w) << 16);
    reinterpret_cast<uint2*>(out)[i] = make_uint2(lo, hi);
  }
}

// ---------------- fp32 [R][C] -> bf16 [C][R] transpose ----------------
__global__ __launch_bounds__(256)
void transpose_bf16(const float* __restrict__ in, u16* __restrict__ out, int R, int C) {
  __shared__ float tile[32][33];
  const int c0 = blockIdx.x * 32, r0 = blockIdx.y * 32;
  const int tx = threadIdx.x, ty = threadIdx.y;
#pragma unroll
  for (int i = 0; i < 4; i++)
    tile[ty + 8 * i][tx] = in[(size_t)(r0 + ty + 8 * i) * C + c0 + tx];
  __syncthreads();
#pragma unroll
  for (int i = 0; i < 4; i++)
    out[(size_t)(c0 + ty + 8 * i) * R + r0 + tx] = f32_bf16(tile[tx][ty + 8 * i]);
}

// ---------------- bf16 GEMM: C[M][N] = A[M][K] * Bt[N][K]^T + bias ----------------
// MODE 0: scatter into Q (pre-scaled by SCALE*log2e) [BH][S][64], K [BH][S][64],
//         Vt [BH][64][S] (bf16)
// MODE 1: fp32 out [M][N]
template <int MODE>
__global__ __launch_bounds__(256)
void gemm_bf16(const u16* __restrict__ A, const u16* __restrict__ Bt,
               const float* __restrict__ bias,
               u16* __restrict__ q_out, u16* __restrict__ k_out,
               u16* __restrict__ vt_out, float* __restrict__ f_out,
               int M, int N, int K) {
  constexpr int BK = 32;
  __shared__ u16 lds_a[128 * BK];
  __shared__ u16 lds_b[128 * BK];
  const int m0 = blockIdx.x * 128;
  const int n0 = blockIdx.y * 128;
  const int t = threadIdx.x;
  const int lane = t & 63;
  const int w = t >> 6;
  const int wr = w >> 1, wc = w & 1;        // 2x2 wave grid, 64x64 per wave
  const int fr = lane & 15, fq = lane >> 4; // fragment row/col group

  const u16* ga0 = A + (size_t)(m0 + (t >> 2)) * K + (t & 3) * 8;
  const u16* ga1 = ga0 + (size_t)64 * K;
  const u16* gb0 = Bt + (size_t)(n0 + (t >> 2)) * K + (t & 3) * 8;
  const u16* gb1 = gb0 + (size_t)64 * K;
  u16* la0 = lds_a + t * 8;
  u16* la1 = lds_a + (t + 256) * 8;
  u16* lb0 = lds_b + t * 8;
  u16* lb1 = lds_b + (t + 256) * 8;

  f32x4 acc[4][4] = {};

  for (int k0 = 0; k0 < K; k0 += BK) {
    __syncthreads();
    gload_lds16(ga0, la0);
    gload_lds16(ga1, la1);
    gload_lds16(gb0, lb0);
    gload_lds16(gb1, lb1);
    ga0 += BK; ga1 += BK; gb0 += BK; gb1 += BK;
    __syncthreads();
    bf16x8 af[4], bfr[4];
#pragma unroll
    for (int i = 0; i < 4; i++)
      af[i] = *reinterpret_cast<const bf16x8*>(lds_a + (wr * 64 + i * 16 + fr) * BK + fq * 8);
#pragma unroll
    for (int i = 0; i < 4; i++)
      bfr[i] = *reinterpret_cast<const bf16x8*>(lds_b + (wc * 64 + i * 16 + fr) * BK + fq * 8);
#pragma unroll
    for (int i = 0; i < 4; i++)
#pragma unroll
      for (int j = 0; j < 4; j++)
        acc[i][j] = MFMA16(af[i], bfr[j], acc[i][j]);
  }

#pragma unroll
  for (int i = 0; i < 4; i++) {
#pragma unroll
    for (int j = 0; j < 4; j++) {
      const int ncol = n0 + wc * 64 + j * 16 + fr;
      const float bs = bias[ncol];
#pragma unroll
      for (int r = 0; r < 4; r++) {
        const int mrow = m0 + wr * 64 + i * 16 + fq * 4 + r;
        const float vv = acc[i][j][r] + bs;
        if (MODE == 0) {
          const int which = ncol >> 10;
          const int rem = ncol & 1023;
          const int hh = rem >> 6, dd = rem & 63;
          const int bb = mrow >> 11, ss = mrow & 2047;
          const int bh = bb * 16 + hh;
          if (which == 0)
            q_out[((size_t)bh * SS + ss) * HD + dd] = f32_bf16(vv * SCALE_LOG2E);
          else if (which == 1)
            k_out[((size_t)bh * SS + ss) * HD + dd] = f32_bf16(vv);
          else
            vt_out[((size_t)bh * HD + dd) * SS + ss] = f32_bf16(vv);
        } else {
          f_out[(size_t)mrow * N + ncol] = vv;
        }
      }
    }
  }
}

// ---------------- causal flash attention ----------------
// Q (pre-scaled), K: [BH][S][64] bf16 ; Vt: [BH][64][S] bf16 ; vals: [B][S][D] bf16
// Block = q-tile PAIR (pi, 31-pi): exactly 33 kv-tiles per block (uniform work).
// K/V tiles double-buffered in LDS (XOR-swizzled), staged with global_load_lds.
// Softmax: deferred row-sum (per-lane partials, reduce at flush), defer-max
// rescale (THR=8 log2-units, wave-uniform branch), single-instr exp2/cvt.
__global__ __launch_bounds__(256)
void attn_fwd(const u16* __restrict__ Qb, const u16* __restrict__ Kb,
              const u16* __restrict__ Vt, u16* __restrict__ vals) {
  const int pi = blockIdx.x;  // pair index 0..15 -> q-tiles (pi, 31-pi)
  const int bh = blockIdx.y;  // batch*head
  const u16* Qp = Qb + (size_t)bh * SS * HD;
  const char* Kp = (const char*)(Kb + (size_t)bh * SS * HD);
  const char* Vp = (const char*)(Vt + (size_t)bh * HD * SS);
  const int t = threadIdx.x, lane = t & 63, w = t >> 6;
  const int fr = lane & 15, fq = lane >> 4;
  const int swz = (fr & 7) << 4; // row&7 == fr&7 for all fragment rows used below

  __shared__ u16 kbuf[2][4096]; // [64 rows][128B] swizzled, 8KB each
  __shared__ u16 vbuf[2][4096]; // [64 d-rows][128B keys] swizzled
  __shared__ u16 plds[4][16][72];
  u16* myp = &plds[w][0][0];

  const int qtA = pi, qtB = 31 - pi;
  const int nA = qtA + 1, nTot = nA + qtB + 1; // == 33

  const int lin0 = t * 16; // staging byte offset, round 0

  // loop-invariant swizzled LDS fragment offsets (static-indexed -> registers)
  int offKV[8];
#pragma unroll
  for (int kf = 0; kf < 4; kf++)
#pragma unroll
    for (int kk = 0; kk < 2; kk++)
      offKV[kf * 2 + kk] = (kf * 16 + fr) * 128 + ((kk * 64 + fq * 16) ^ swz);

  bf16x8 aq[2];
  {
    const int qbase = qtA * 64 + w * 16;
#pragma unroll
    for (int kk = 0; kk < 2; kk++)
      aq[kk] = *reinterpret_cast<const bf16x8*>(Qp + (size_t)(qbase + fr) * HD + kk * 32 + fq * 8);
  }

  f32x4 o[4] = {};
  float mrun[4], lpart[4];
#pragma unroll
  for (int j = 0; j < 4; j++) { mrun[j] = -3e38f; lpart[j] = 0.f; }

#define STAGE(bufi, kvt_)                                                     \
  {                                                                           \
    _Pragma("unroll")                                                         \
    for (int r = 0; r < 2; r++) {                                             \
      const int lin = lin0 + r * 4096;                                        \
      const int row = lin >> 7, colb = lin & 127;                             \
      const int scol = colb ^ ((row & 7) << 4);                               \
      gload_lds16(Kp + (size_t)((kvt_) * 64 + row) * 128 + scol,              \
                  &kbuf[bufi][lin >> 1]);                                     \
      gload_lds16(Vp + (size_t)row * 4096 + (kvt_) * 128 + scol,              \
                  &vbuf[bufi][lin >> 1]);                                     \
    }                                                                         \
  }

  auto write_out = [&](int qt) {
    const int b_ = bh >> 4, h_ = bh & 15;
    const int qb = qt * 64 + w * 16;
    float linv[4];
#pragma unroll
    for (int j = 0; j < 4; j++) {
      float rs = lpart[j];
#pragma unroll
      for (int off = 1; off < 16; off <<= 1)
        rs += __shfl_xor(rs, off, 64);
      linv[j] = 1.f / rs;
    }
#pragma unroll
    for (int df = 0; df < 4; df++)
#pragma unroll
      for (int j = 0; j < 4; j++) {
        const float vv = o[df][j] * linv[j];
        const int qg = qb + fq * 4 + j;
        vals[((size_t)(b_ * SS + qg)) * D + h_ * HD + df * 16 + fr] = cvt_bf16_1(vv);
      }
  };

  int cur = 0;
  STAGE(0, 0);
  asm volatile("s_waitcnt vmcnt(0)" ::: "memory");
  __syncthreads();

  for (int ti = 0; ti < nTot; ++ti) {
    const bool segB = ti >= nA;
    const int kvt = segB ? ti - nA : ti;
    const int qt = segB ? qtB : qtA;
    // prefetch next kv tile (kv tiles are qt-independent, so the pipeline
    // runs flat across the segment boundary)
    if (ti + 1 < nTot) {
      const int nk = (ti + 1 >= nA) ? (ti + 1 - nA) : (ti + 1);
      STAGE(cur ^ 1, nk);
    }
    if (ti == nA) { // segment switch: flush A, reset state for B
      write_out(qtA);
      const int qbase = qtB * 64 + w * 16;
#pragma unroll
      for (int kk = 0; kk < 2; kk++)
        aq[kk] = *reinterpret_cast<const bf16x8*>(Qp + (size_t)(qbase + fr) * HD + kk * 32 + fq * 8);
#pragma unroll
      for (int j = 0; j < 4; j++) { mrun[j] = -3e38f; lpart[j] = 0.f; }
#pragma unroll
      for (int df = 0; df < 4; df++) o[df] = f32x4{0.f, 0.f, 0.f, 0.f};
    }

    const char* kb = (const char*)kbuf[cur];
    const char* vb = (const char*)vbuf[cur];

    // S = Q K^T (Q pre-scaled by SCALE*log2e -> scores already in log2 units)
    f32x4 sc[4] = {};
#pragma unroll
    for (int kf = 0; kf < 4; kf++) {
#pragma unroll
      for (int kk = 0; kk < 2; kk++) {
        bf16x8 bk = *reinterpret_cast<const bf16x8*>(kb + offKV[kf * 2 + kk]);
        sc[kf] = MFMA16(aq[kk], bk, sc[kf]);
      }
    }
    // causal mask: diagonal tile only
    if (kvt == qt) {
#pragma unroll
      for (int kf = 0; kf < 4; kf++)
#pragma unroll
        for (int j = 0; j < 4; j++) {
          const int keyl = kf * 16 + fr;
          const int ql = w * 16 + fq * 4 + j;
          if (keyl > ql) sc[kf][j] = -3e38f;
        }
    }
    // online softmax: tile max per row (rows live across fr lanes)
    float mj[4];
#pragma unroll
    for (int j = 0; j < 4; j++) {
      float m = fmaxf(fmaxf(sc[0][j], sc[1][j]), fmaxf(sc[2][j], sc[3][j]));
#pragma unroll
      for (int off = 1; off < 16; off <<= 1)
        m = fmaxf(m, __shfl_xor(m, off, 64));
      mj[j] = m;
    }
    // defer-max: only rescale when a row max grew by > 8 (log2 units)
    const bool need = (mj[0] > mrun[0] + 8.f) | (mj[1] > mrun[1] + 8.f) |
                      (mj[2] > mrun[2] + 8.f) | (mj[3] > mrun[3] + 8.f);
    if (__any((int)need)) {
#pragma unroll
      for (int j = 0; j < 4; j++) {
        const float mnew = fmaxf(mrun[j], mj[j]);
        const float alpha = exp2_fast(mrun[j] - mnew);
        mrun[j] = mnew;
        lpart[j] *= alpha;
#pragma unroll
        for (int df = 0; df < 4; df++) o[df][j] *= alpha;
      }
    }
    // P = exp2(S - m); accumulate per-lane partial row-sums (reduced at flush)
#pragma unroll
    for (int j = 0; j < 4; j++) {
#pragma unroll
      for (int kf = 0; kf < 4; kf++) {
        const float p = exp2_fast(sc[kf][j] - mrun[j]);
        sc[kf][j] = p;
        lpart[j] += p;
      }
    }
    // P -> per-wave LDS (bf16), then read A-fragments (wave-internal DS ordering)
#pragma unroll
    for (int kf = 0; kf < 4; kf++)
#pragma unroll
      for (int j = 0; j < 4; j++)
        myp[(fq * 4 + j) * 72 + kf * 16 + fr] = cvt_bf16_1(sc[kf][j]);
    bf16x8 pa[2];
#pragma unroll
    for (int kk = 0; kk < 2; kk++)
      pa[kk] = *reinterpret_cast<const bf16x8*>(myp + fr * 72 + kk * 32 + fq * 8);
    // O += P V  (V tile in LDS: [d-row][key] swizzled; same offsets as K)
#pragma unroll
    for (int df = 0; df < 4; df++) {
#pragma unroll
      for (int kk = 0; kk < 2; kk++) {
        bf16x8 bv = *reinterpret_cast<const bf16x8*>(vb + offKV[df * 2 + kk]);
        o[df] = MFMA16(pa[kk], bv, o[df]);
      }
    }

    asm volatile("s_waitcnt vmcnt(0)" ::: "memory");
    __syncthreads();
    cur ^= 1;
  }
  write_out(qtB);
#undef STAGE
}

extern "C" void kernel_launch(void* const* d_in, const int* in_sizes, int n_in,
                              void* d_out, int out_size, void* d_ws, size_t ws_size,
                              hipStream_t stream) {
  const float* x = (const float*)d_in[0];
  const float* Wqkv = (const float*)d_in[1];
  const float* bqkv = (const float*)d_in[2];
  const float* Wout = (const float*)d_in[3];
  const float* bout = (const float*)d_in[4];
  float* out = (float*)d_out;

  char* p = (char*)d_ws;
  u16* xb = (u16*)p;    p += (size_t)MTOK * D * 2;       // 16.8 MB
  u16* wqkvT = (u16*)p; p += (size_t)3 * D * D * 2;      // 6.3 MB
  u16* woutT = (u16*)p; p += (size_t)D * D * 2;          // 2.1 MB
  u16* Qb = (u16*)p;    p += (size_t)BH * SS * HD * 2;   // 16.8 MB
  u16* Kb = (u16*)p;    p += (size_t)BH * SS * HD * 2;   // 16.8 MB
  u16* Vt = (u16*)p;    p += (size_t)BH * SS * HD * 2;   // 16.8 MB
  u16* vals = (u16*)p;  p += (size_t)MTOK * D * 2;       // 16.8 MB  (total ~92 MB)

  cvt_bf16<<<2048, 256, 0, stream>>>(x, xb, MTOK * D / 4);
  transpose_bf16<<<dim3(3 * D / 32, D / 32), dim3(32, 8), 0, stream>>>(Wqkv, wqkvT, D, 3 * D);
  transpose_bf16<<<dim3(D / 32, D / 32), dim3(32, 8), 0, stream>>>(Wout, woutT, D, D);
  gemm_bf16<0><<<dim3(MTOK / 128, 3 * D / 128), 256, 0, stream>>>(
      xb, wqkvT, bqkv, Qb, Kb, Vt, nullptr, MTOK, 3 * D, D);
  attn_fwd<<<dim3(16, BH), 256, 0, stream>>>(Qb, Kb, Vt, vals);
  gemm_bf16<1><<<dim3(MTOK / 128, D / 128), 256, 0, stream>>>(
      vals, woutT, bout, nullptr, nullptr, nullptr, out, MTOK, D, D);
}